// Round 9
// baseline (499.719 us; speedup 1.0000x reference)
//
#include <hip/hip_runtime.h>
#include <hip/hip_bf16.h>

#define DEVI __device__ __forceinline__
#define AS1 __attribute__((address_space(1)))
#define AS3 __attribute__((address_space(3)))

typedef short bf16x8 __attribute__((ext_vector_type(8)));
typedef float f32x4  __attribute__((ext_vector_type(4)));

// Problem constants (B=32, H=W=56, C=256, wh=ww=7, shift=3, heads=8, hd=32)
constexpr int MROWS = 100352;            // 32 * 64 * 49 window-order rows

// window-order row -> flat token index (b*3136 + h*56 + w).
DEVI int win_row_to_token(int r) {
  int b   = r / 3136;
  int rem = r - b * 3136;
  int wi  = rem / 49;
  int t   = rem - wi * 49;
  int nwh = wi >> 3, nww = wi & 7;
  int th = t / 7, tw = t - th * 7;
  int h = nwh * 7 + th + 3; if (h >= 56) h -= 56;
  int w = nww * 7 + tw + 3; if (w >= 56) w -= 56;
  return b * 3136 + h * 56 + w;
}

DEVI unsigned short f2bf(float f) {
  __hip_bfloat16 h = __float2bfloat16(f);
  return __builtin_bit_cast(unsigned short, h);
}

// ---------------- fp32 -> bf16 weight convert ----------------
__global__ void cvt_kernel(const float* __restrict__ in, __hip_bfloat16* __restrict__ out, int n) {
  int i = blockIdx.x * 256 + threadIdx.x;
  if (i < n) out[i] = __float2bfloat16(in[i]);
}

// ---------------- LayerNorm (one wave per token row, C=256) ----------------
template<bool WIN>
__global__ __launch_bounds__(256) void ln_kernel(
    const float* __restrict__ xin, const float* __restrict__ g,
    const float* __restrict__ b, __hip_bfloat16* __restrict__ outb)
{
  int r = blockIdx.x * 4 + (threadIdx.x >> 6);
  int l = threadIdx.x & 63;
  int tok = WIN ? win_row_to_token(r) : r;
  float4 xv = *(const float4*)&xin[(size_t)tok * 256 + l * 4];
  float s = xv.x + xv.y + xv.z + xv.w;
  float q = xv.x * xv.x + xv.y * xv.y + xv.z * xv.z + xv.w * xv.w;
  #pragma unroll
  for (int off = 32; off; off >>= 1) { s += __shfl_xor(s, off); q += __shfl_xor(q, off); }
  float mu = s * (1.0f / 256.0f);
  float var = q * (1.0f / 256.0f) - mu * mu;
  float rs = rsqrtf(var + 1e-5f);
  float4 gv = *(const float4*)&g[l * 4];
  float4 bv = *(const float4*)&b[l * 4];
  ushort4 st;
  st.x = f2bf((xv.x - mu) * rs * gv.x + bv.x);
  st.y = f2bf((xv.y - mu) * rs * gv.y + bv.y);
  st.z = f2bf((xv.z - mu) * rs * gv.z + bv.z);
  st.w = f2bf((xv.w - mu) * rs * gv.w + bv.w);
  *(ushort4*)&outb[(size_t)r * 256 + l * 4] = st;
}

enum { EPI_QKV = 0, EPI_PROJ = 1, EPI_MLP1 = 2, EPI_MLP2 = 3 };

// ------------- persistent strip GEMM v4: 2 blocks/CU for overlap -------------
// 512 blocks (2/CU), 256 thr = 4 waves (2Mx2N), wave tile 64x64, block tile
// 128(M)x128(N). LDS 80KB total -> exactly 2 blocks/CU: B panel [128n][256k]
// 64KB (XOR-swizzled; staged once per nt for K=256, per kb-quarter for K=1024)
// + SINGLE A buffer [128m][64k] 16KB. Per chunk: vmcnt(0); barrier; compute;
// barrier; stage-next. Within-block stage latency is covered by the OTHER
// block on the CU (m114/m97 mechanism) — the independent barrier group that
// strip3 (1 block/CU) lacked. Next-tile A issue precedes the epilogue so the
// GELU/store burst covers its latency.
template<int EPI, int KTOT>
__global__ __launch_bounds__(256) void strip4(
    const __hip_bfloat16* __restrict__ A,
    const __hip_bfloat16* __restrict__ Bw,
    int ntiles,                        // N/128
    const float* __restrict__ bias,
    const float* __restrict__ xres,    // PROJ: original x (token order)
    float* __restrict__ outf,          // PROJ/MLP2: d_out
    __hip_bfloat16* __restrict__ outb) // QKV/MLP1
{
  constexpr int NKB = KTOT / 256;            // B slices per tile (1 or 4)
  constexpr int NCH = NKB * 4;               // chunks per tile
  constexpr int K2  = KTOT * 2;              // row byte stride
  constexpr long TSTRIDE = 128L * K2;        // A tile byte stride
  __shared__ __align__(16) __hip_bfloat16 Bl[128 * 256];   // 64KB
  __shared__ __align__(16) __hip_bfloat16 Al[128 * 64];    // 16KB

  const int tid = threadIdx.x;
  const int w = tid >> 6, l = tid & 63;
  const int wr = w >> 1, wc = w & 1;         // 2 M-waves x 2 N-waves
  const int g = l >> 4, lm = l & 15;

  const int xcd = blockIdx.x & 7;
  const int cu2 = blockIdx.x >> 3;           // 0..63
  const int T   = 98 * ntiles;               // tiles per XCD chunk (98 mt x nt)
  const int t0  = (cu2 * T) >> 6;
  const int t1  = ((cu2 + 1) * T) >> 6;

  char* AlB = (char*)Al;
  char* BlB = (char*)Bl;

  // ---- per-lane hoisted constants ----
  const int  dstW = w * 1024;                // LDS stage dst (wave-uniform; HW adds lane*16)
  const long aoff = (long)(tid >> 3) * K2 + (((tid & 7) ^ ((tid >> 3) & 7)) << 4);
  const long boff = (long)(tid >> 5) * K2 + (((tid & 31) ^ ((tid >> 5) & 7)) << 4);
  const int  bA = (wr * 64 + lm) * 128 + ((g ^ (lm & 7)) << 4);  // ^kk*64, +mi*2048
  const int  bB = (wc * 64 + lm) * 512 + ((g ^ (lm & 7)) << 4);  // ^kk*64, +c4*128, +ni*8192

  int nt = t0 / 98;
  int mtoff = t0 - nt * 98;
  const char* Ab = (const char*)A + (long)xcd * 98 * TSTRIDE;
  const char* At = Ab + (long)mtoff * TSTRIDE;

  auto issueA = [&](const char* Atile, int ch) {
    #pragma unroll
    for (int j = 0; j < 4; ++j)
      __builtin_amdgcn_global_load_lds(
          (const AS1 void*)(Atile + aoff + j * (32L * K2) + ch * 128),
          (AS3 void*)(AlB + j * 4096 + dstW), 16, 0, 0);
  };
  auto stageB = [&](int nt_, int kb_) {
    const char* Bb = (const char*)Bw + (long)nt_ * 128 * K2 + kb_ * 512;
    #pragma unroll
    for (int j = 0; j < 16; ++j)
      __builtin_amdgcn_global_load_lds(
          (const AS1 void*)(Bb + boff + j * (8L * K2)),
          (AS3 void*)(BlB + j * 4096 + dstW), 16, 0, 0);
  };

  // ---- prologue ----
  stageB(nt, 0);
  issueA(At, 0);

  f32x4 acc[4][4];
  for (int t = t0; t < t1; ++t) {
    const bool wrap = (mtoff == 97);
    const char* Atn = wrap ? Ab : (At + TSTRIDE);
    const int ntn = wrap ? nt + 1 : nt;
    #pragma unroll
    for (int mi = 0; mi < 4; ++mi)
      #pragma unroll
      for (int ni = 0; ni < 4; ++ni)
        acc[mi][ni] = f32x4{0.f, 0.f, 0.f, 0.f};

    #pragma unroll
    for (int kb = 0; kb < NKB; ++kb) {
      #pragma unroll
      for (int c4 = 0; c4 < 4; ++c4) {
        const int ch = kb * 4 + c4;
        asm volatile("s_waitcnt vmcnt(0)" ::: "memory");   // own staged loads landed
        __builtin_amdgcn_s_barrier();                      // everyone's landed
        asm volatile("" ::: "memory");

        #pragma unroll
        for (int kk = 0; kk < 2; ++kk) {
          bf16x8 af[4], bf[4];
          const int ax = bA ^ (kk << 6);
          const int bx = bB ^ (kk << 6);
          #pragma unroll
          for (int mi = 0; mi < 4; ++mi)
            af[mi] = *(const bf16x8*)(AlB + ax + mi * 2048);
          #pragma unroll
          for (int ni = 0; ni < 4; ++ni)
            bf[ni] = *(const bf16x8*)(BlB + bx + c4 * 128 + ni * 8192);
          #pragma unroll
          for (int mi = 0; mi < 4; ++mi)
            #pragma unroll
            for (int ni = 0; ni < 4; ++ni)
              acc[mi][ni] = __builtin_amdgcn_mfma_f32_16x16x32_bf16(
                  af[mi], bf[ni], acc[mi][ni], 0, 0, 0);
        }

        asm volatile("" ::: "memory");
        __builtin_amdgcn_s_barrier();                      // reads done -> safe to overwrite
        // stage next chunk (latency covered by the other block / epilogue)
        if (ch < NCH - 1) {
          if (NKB > 1 && c4 == 3) stageB(nt, kb + 1);
          issueA(At, ch + 1);
        } else if (t < t1 - 1) {
          if (NKB > 1) stageB(ntn, 0);                     // kb wraps -> restage
          else if (ntn != nt) stageB(ntn, 0);              // rare: nt change
          issueA(Atn, 0);
        }
      }
    }

    // ---- tile epilogue (regs + global only) ----
    {
      const int mt = xcd * 98 + mtoff;
      #pragma unroll
      for (int mi = 0; mi < 4; ++mi)
        #pragma unroll
        for (int j = 0; j < 4; ++j) {
          int grow = mt * 128 + wr * 64 + mi * 16 + g * 4 + j;
          int orow = grow;
          if (EPI == EPI_PROJ) orow = win_row_to_token(grow);
          #pragma unroll
          for (int ni = 0; ni < 4; ++ni) {
            int gcol = nt * 128 + wc * 64 + ni * 16 + lm;
            float v = acc[mi][ni][j] + bias[gcol];
            if (EPI == EPI_QKV) {
              outb[(size_t)grow * 768 + gcol] = __float2bfloat16(v);
            } else if (EPI == EPI_PROJ) {
              size_t o = (size_t)orow * 256 + gcol;
              outf[o] = xres[o] + v;                       // residual 1
            } else if (EPI == EPI_MLP1) {
              // tanh-form GELU: v * sigmoid(2*0.7978845608*(v + 0.044715 v^3))
              float u2 = v * (1.5957691216f + 0.1426930877f * v * v);
              float e  = __expf(u2);
              float ge = v * e / (e + 1.0f);
              outb[(size_t)grow * 1024 + gcol] = __float2bfloat16(ge);
            } else { // MLP2
              size_t o = (size_t)grow * 256 + gcol;
              outf[o] += v;                                // residual 2 (in-place)
            }
          }
        }
    }

    At = Atn;
    if (wrap) { mtoff = 0; nt = ntn; } else { ++mtoff; }
  }
}

// ---------------- Sadd precompute: bias+mask in MFMA frag layout ----------------
__global__ __launch_bounds__(256) void bias_prep_kernel(
    const float* __restrict__ bt, float* __restrict__ Sadd)
{
  int blk = blockIdx.x;            // class*8 + h
  int cls = blk >> 3, h = blk & 7;
  int re = cls >> 1, ce = cls & 1;
  int lane = threadIdx.x & 63, fs = threadIdx.x >> 6;
  int g = lane >> 4, lm = lane & 15;
  #pragma unroll
  for (int i = 0; i < 4; ++i) {
    int f = fs * 4 + i;
    int mi = f >> 2, ni = f & 3;
    int key = ni * 16 + lm;
    f32x4 v;
    #pragma unroll
    for (int j = 0; j < 4; ++j) {
      int q = mi * 16 + g * 4 + j;
      float val;
      if (key >= 49) {
        val = -1e30f;
      } else {
        int qq = q > 48 ? 48 : q;
        int qh = qq / 7, qw = qq - qh * 7;
        int kh = key / 7, kw = key - kh * 7;
        int rpi = (qh - kh + 6) * 13 + (qw - kw + 6);
        val = bt[rpi * 8 + h];
        int rq = (re ? (qh < 4 ? 1 : 2) : 0) * 3 + (ce ? (qw < 4 ? 1 : 2) : 0);
        int rk = (re ? (kh < 4 ? 1 : 2) : 0) * 3 + (ce ? (kw < 4 ? 1 : 2) : 0);
        if (rq != rk) val -= 100.0f;
      }
      v[j] = val;
    }
    ((f32x4*)Sadd)[(blk * 16 + f) * 64 + lane] = v;
  }
}

// ---------------- MFMA attention: block = (window, 4 heads), wave = head ----------
__global__ __launch_bounds__(256) void attn_mfma_kernel(
    const __hip_bfloat16* __restrict__ qkv,
    const float* __restrict__ Sadd,
    __hip_bfloat16* __restrict__ attn_out)
{
  __shared__ __align__(16) __hip_bfloat16 Pl[4][64 * 72];
  int blk = blockIdx.x;
  int win = blk >> 1, half = blk & 1;
  int w = threadIdx.x >> 6, l = threadIdx.x & 63;
  int head = half * 4 + w;
  int g = l >> 4, lm = l & 15;
  int wi = win & 63;
  int cls = (((wi >> 3) == 7) ? 2 : 0) | (((wi & 7) == 7) ? 1 : 0);
  const __hip_bfloat16* base = qkv + (size_t)win * 49 * 768 + head * 32;

  bf16x8 aQ[4], bK[4];
  #pragma unroll
  for (int mi = 0; mi < 4; ++mi) {
    int q = mi * 16 + lm; if (q > 48) q = 48;
    aQ[mi] = *(const bf16x8*)(base + q * 768 + g * 8);
  }
  #pragma unroll
  for (int ni = 0; ni < 4; ++ni) {
    int k = ni * 16 + lm; if (k > 48) k = 48;
    bK[ni] = *(const bf16x8*)(base + 256 + k * 768 + g * 8);
  }
  f32x4 acc[4][4] = {};
  #pragma unroll
  for (int mi = 0; mi < 4; ++mi)
    #pragma unroll
    for (int ni = 0; ni < 4; ++ni)
      acc[mi][ni] = __builtin_amdgcn_mfma_f32_16x16x32_bf16(aQ[mi], bK[ni], acc[mi][ni], 0, 0, 0);

  const float scale = 0.17677669529663687f;
  const f32x4* Sb = (const f32x4*)Sadd + (size_t)(cls * 8 + head) * 16 * 64 + l;

  f32x4 rsum[4];
  __hip_bfloat16* P = Pl[w];
  #pragma unroll
  for (int mi = 0; mi < 4; ++mi) {
    #pragma unroll
    for (int ni = 0; ni < 4; ++ni) {
      f32x4 sv = Sb[(mi * 4 + ni) * 64];
      #pragma unroll
      for (int j = 0; j < 4; ++j) acc[mi][ni][j] = acc[mi][ni][j] * scale + sv[j];
    }
    f32x4 mx = acc[mi][0];
    #pragma unroll
    for (int ni = 1; ni < 4; ++ni)
      #pragma unroll
      for (int j = 0; j < 4; ++j) mx[j] = fmaxf(mx[j], acc[mi][ni][j]);
    #pragma unroll
    for (int msk = 1; msk < 16; msk <<= 1)
      #pragma unroll
      for (int j = 0; j < 4; ++j) mx[j] = fmaxf(mx[j], __shfl_xor(mx[j], msk));
    f32x4 sm = {};
    #pragma unroll
    for (int ni = 0; ni < 4; ++ni)
      #pragma unroll
      for (int j = 0; j < 4; ++j) {
        float e = __expf(acc[mi][ni][j] - mx[j]);
        acc[mi][ni][j] = e;
        sm[j] += e;
      }
    #pragma unroll
    for (int msk = 1; msk < 16; msk <<= 1)
      #pragma unroll
      for (int j = 0; j < 4; ++j) sm[j] += __shfl_xor(sm[j], msk);
    rsum[mi] = sm;
    #pragma unroll
    for (int ni = 0; ni < 4; ++ni)
      #pragma unroll
      for (int j = 0; j < 4; ++j) {
        int q = mi * 16 + g * 4 + j;
        int key = ni * 16 + lm;
        P[q * 72 + key] = __float2bfloat16(acc[mi][ni][j]);
      }
  }

  bf16x8 bV[2][2];
  #pragma unroll
  for (int s = 0; s < 2; ++s)
    #pragma unroll
    for (int n2 = 0; n2 < 2; ++n2) {
      bf16x8 vv;
      #pragma unroll
      for (int e = 0; e < 8; ++e) {
        int key = s * 32 + g * 8 + e; if (key > 48) key = 48;
        vv[e] = __builtin_bit_cast(short, base[512 + key * 768 + n2 * 16 + lm]);
      }
      bV[s][n2] = vv;
    }

  f32x4 o[4][2] = {};
  #pragma unroll
  for (int s = 0; s < 2; ++s)
    #pragma unroll
    for (int mi2 = 0; mi2 < 4; ++mi2) {
      bf16x8 aP = *(const bf16x8*)&P[(mi2 * 16 + lm) * 72 + s * 32 + g * 8];
      #pragma unroll
      for (int n2 = 0; n2 < 2; ++n2)
        o[mi2][n2] = __builtin_amdgcn_mfma_f32_16x16x32_bf16(aP, bV[s][n2], o[mi2][n2], 0, 0, 0);
    }

  #pragma unroll
  for (int mi2 = 0; mi2 < 4; ++mi2) {
    f32x4 li;
    #pragma unroll
    for (int j = 0; j < 4; ++j) li[j] = 1.0f / rsum[mi2][j];
    #pragma unroll
    for (int n2 = 0; n2 < 2; ++n2)
      #pragma unroll
      for (int j = 0; j < 4; ++j) {
        int q = mi2 * 16 + g * 4 + j;
        if (q < 49)
          attn_out[((size_t)win * 49 + q) * 256 + head * 32 + n2 * 16 + lm] =
              __float2bfloat16(o[mi2][n2][j] * li[j]);
      }
  }
}

// ---------------- host launch ----------------
extern "C" void kernel_launch(void* const* d_in, const int* in_sizes, int n_in,
                              void* d_out, int out_size, void* d_ws, size_t ws_size,
                              hipStream_t stream) {
  const float* x          = (const float*)d_in[0];
  const float* g1         = (const float*)d_in[1];
  const float* b1         = (const float*)d_in[2];
  const float* qkv_w      = (const float*)d_in[3];
  const float* qkv_b      = (const float*)d_in[4];
  const float* bias_table = (const float*)d_in[5];
  const float* proj_w     = (const float*)d_in[6];
  const float* proj_b     = (const float*)d_in[7];
  const float* g2         = (const float*)d_in[8];
  const float* b2         = (const float*)d_in[9];
  const float* w1         = (const float*)d_in[10];
  const float* bm1        = (const float*)d_in[11];
  const float* w2         = (const float*)d_in[12];
  const float* bm2        = (const float*)d_in[13];
  float* out = (float*)d_out;

  char* ws = (char*)d_ws;
  __hip_bfloat16* A_ln   = (__hip_bfloat16*)(ws);
  __hip_bfloat16* qkvb   = (__hip_bfloat16*)(ws + 51380224);
  __hip_bfloat16* attn_o = (__hip_bfloat16*)(ws + 205520896);
  __hip_bfloat16* hidden = qkvb;
  __hip_bfloat16* qkv_wb  = (__hip_bfloat16*)(ws + 256901120);
  __hip_bfloat16* proj_wb = qkv_wb + 196608;
  __hip_bfloat16* w1b     = proj_wb + 65536;
  __hip_bfloat16* w2b     = w1b + 262144;
  float* Sadd = (float*)(ws + 258473984);

  cvt_kernel<<<(196608 + 255) / 256, 256, 0, stream>>>(qkv_w, qkv_wb, 196608);
  cvt_kernel<<<(65536  + 255) / 256, 256, 0, stream>>>(proj_w, proj_wb, 65536);
  cvt_kernel<<<(262144 + 255) / 256, 256, 0, stream>>>(w1, w1b, 262144);
  cvt_kernel<<<(262144 + 255) / 256, 256, 0, stream>>>(w2, w2b, 262144);
  bias_prep_kernel<<<32, 256, 0, stream>>>(bias_table, Sadd);

  ln_kernel<true><<<MROWS / 4, 256, 0, stream>>>(x, g1, b1, A_ln);

  strip4<EPI_QKV, 256><<<512, 256, 0, stream>>>(
      A_ln, qkv_wb, 6, qkv_b, nullptr, nullptr, qkvb);

  attn_mfma_kernel<<<4096, 256, 0, stream>>>(qkvb, Sadd, attn_o);

  strip4<EPI_PROJ, 256><<<512, 256, 0, stream>>>(
      attn_o, proj_wb, 2, proj_b, x, out, nullptr);

  ln_kernel<false><<<MROWS / 4, 256, 0, stream>>>(out, g2, b2, A_ln);

  strip4<EPI_MLP1, 256><<<512, 256, 0, stream>>>(
      A_ln, w1b, 8, bm1, nullptr, nullptr, hidden);

  strip4<EPI_MLP2, 1024><<<512, 256, 0, stream>>>(
      hidden, w2b, 2, bm2, nullptr, out, nullptr);
}